// Round 1
// baseline (165.728 us; speedup 1.0000x reference)
//
#include <hip/hip_runtime.h>
#include <math.h>

#define B_ 2
#define C_ 256
#define H_ 64
#define W_ 64
#define L_ (H_*W_)      // 4096
#define HEADS_ 8
#define DH_ 32          // head dim
#define K_ 7
#define PAD_ 3
#define K2_ 49

// ---------------- Kernel 1: fused QKV projection, NCHW in -> NHWC out -------
// out[(b*L + l)*C + o] = bias[o] + sum_c in[(b*C + c)*L + l] * w[o*C + c]
// grid: (L/64, C/64, B*3), block (16,16). tx -> o (coalesced float4 writes), ty -> l.
__global__ __launch_bounds__(256) void qkv_proj(
    const float* __restrict__ q_in, const float* __restrict__ k_in, const float* __restrict__ v_in,
    const float* __restrict__ wq, const float* __restrict__ bq,
    const float* __restrict__ wk, const float* __restrict__ bk,
    const float* __restrict__ wv, const float* __restrict__ bv,
    float* __restrict__ qt, float* __restrict__ kt, float* __restrict__ vt)
{
    const int which = blockIdx.z % 3;
    const int b = blockIdx.z / 3;
    const float* in   = (which==0) ? q_in : (which==1 ? k_in : v_in);
    const float* w    = (which==0) ? wq   : (which==1 ? wk   : wv);
    const float* bias = (which==0) ? bq   : (which==1 ? bk   : bv);
    float* out        = (which==0) ? qt   : (which==1 ? kt   : vt);

    const int l0 = blockIdx.x * 64;
    const int o0 = blockIdx.y * 64;
    const int tx = threadIdx.x, ty = threadIdx.y;
    const int tid = ty*16 + tx;

    __shared__ float As[16][68]; // [c][l]
    __shared__ float Bs[16][68]; // [c][o]

    float acc[4][4] = {}; // [li][oi]

    for (int c0 = 0; c0 < C_; c0 += 16) {
        #pragma unroll
        for (int i = 0; i < 4; ++i) {
            int idx = tid + i*256;
            int c = idx >> 6, l = idx & 63;
            As[c][l] = in[(size_t)(b*C_ + c0 + c)*L_ + l0 + l];
        }
        #pragma unroll
        for (int i = 0; i < 4; ++i) {
            int idx = tid + i*256;
            int o = idx >> 4, c = idx & 15;
            Bs[c][o] = w[(size_t)(o0 + o)*C_ + c0 + c];
        }
        __syncthreads();
        #pragma unroll
        for (int cc = 0; cc < 16; ++cc) {
            float a[4], bb[4];
            #pragma unroll
            for (int i=0;i<4;++i) a[i]  = As[cc][ty*4+i];
            #pragma unroll
            for (int i=0;i<4;++i) bb[i] = Bs[cc][tx*4+i];
            #pragma unroll
            for (int li=0;li<4;++li)
                #pragma unroll
                for (int oi=0;oi<4;++oi)
                    acc[li][oi] += a[li]*bb[oi];
        }
        __syncthreads();
    }
    #pragma unroll
    for (int li=0;li<4;++li) {
        int l = l0 + ty*4 + li;
        float4 r;
        r.x = acc[li][0] + bias[o0+tx*4+0];
        r.y = acc[li][1] + bias[o0+tx*4+1];
        r.z = acc[li][2] + bias[o0+tx*4+2];
        r.w = acc[li][3] + bias[o0+tx*4+3];
        *reinterpret_cast<float4*>(&out[(size_t)(b*L_ + l)*C_ + o0 + tx*4]) = r;
    }
}

// ---------------- Kernel 2: 7x7 local attention per head ----------------
// NHWC(head-major) q/k/v. One wave per (b, h, row y); lane = x.
// OOB taps: logit = 0 (still in softmax denom), V = 0.
__global__ __launch_bounds__(256) void local_attn(
    const float* __restrict__ qt, const float* __restrict__ kt, const float* __restrict__ vt,
    float* __restrict__ at)
{
    const int wave = threadIdx.x >> 6;
    const int lane = threadIdx.x & 63;
    const int y = blockIdx.x*4 + wave;
    const int h = blockIdx.y;
    const int b = blockIdx.z;
    const int x = lane;

    const float scale = 0.0625f; // 1/sqrt(256)

    const size_t base = ((size_t)b*L_)*C_ + h*DH_;

    float4 qv[8];
    {
        const float4* qp = reinterpret_cast<const float4*>(&qt[base + (size_t)(y*W_ + x)*C_]);
        #pragma unroll
        for (int i=0;i<8;++i) qv[i] = qp[i];
    }

    float logits[K2_];
    #pragma unroll
    for (int ky=0; ky<K_; ++ky) {
        int yy = y + ky - PAD_;
        #pragma unroll
        for (int kx=0; kx<K_; ++kx) {
            int xx = x + kx - PAD_;
            float dot = 0.f;
            if (yy >= 0 && yy < H_ && xx >= 0 && xx < W_) {
                const float4* kp = reinterpret_cast<const float4*>(&kt[base + (size_t)(yy*W_ + xx)*C_]);
                #pragma unroll
                for (int i=0;i<8;++i) {
                    float4 kv = kp[i];
                    dot += qv[i].x*kv.x + qv[i].y*kv.y + qv[i].z*kv.z + qv[i].w*kv.w;
                }
            }
            logits[ky*K_+kx] = dot*scale;
        }
    }

    float m = logits[0];
    #pragma unroll
    for (int s=1;s<K2_;++s) m = fmaxf(m, logits[s]);
    float sum = 0.f;
    #pragma unroll
    for (int s=0;s<K2_;++s) { logits[s] = __expf(logits[s]-m); sum += logits[s]; }
    const float inv = 1.0f/sum;

    float4 acc[8] = {};
    #pragma unroll
    for (int ky=0; ky<K_; ++ky) {
        int yy = y + ky - PAD_;
        if (yy < 0 || yy >= H_) continue;
        #pragma unroll
        for (int kx=0; kx<K_; ++kx) {
            int xx = x + kx - PAD_;
            if (xx < 0 || xx >= W_) continue;
            float p = logits[ky*K_+kx]*inv;
            const float4* vp = reinterpret_cast<const float4*>(&vt[base + (size_t)(yy*W_ + xx)*C_]);
            #pragma unroll
            for (int i=0;i<8;++i) {
                float4 vv = vp[i];
                acc[i].x += p*vv.x; acc[i].y += p*vv.y; acc[i].z += p*vv.z; acc[i].w += p*vv.w;
            }
        }
    }
    float4* op = reinterpret_cast<float4*>(&at[base + (size_t)(y*W_ + x)*C_]);
    #pragma unroll
    for (int i=0;i<8;++i) op[i] = acc[i];
}

// ---------------- Kernel 3: output projection, NHWC -> NCHW ----------------
// out[(b*C + o)*L + l] = bo[o] + sum_c at[(b*L + l)*C + c] * wo[o*C + c]
// grid (L/64, C/64, B), block (16,16). tx -> l (coalesced float4 writes), ty -> o.
__global__ __launch_bounds__(256) void out_proj(
    const float* __restrict__ at, const float* __restrict__ wo, const float* __restrict__ bo,
    float* __restrict__ out)
{
    const int b = blockIdx.z;
    const int l0 = blockIdx.x*64;
    const int o0 = blockIdx.y*64;
    const int tx = threadIdx.x, ty = threadIdx.y;
    const int tid = ty*16+tx;

    __shared__ float As[16][68]; // [c][l]
    __shared__ float Bs[16][68]; // [c][o]

    float acc[4][4] = {}; // [oi][li]

    for (int c0=0;c0<C_;c0+=16) {
        #pragma unroll
        for (int i=0;i<4;++i) {
            int idx = tid + i*256;
            int l = idx >> 4, c = idx & 15;
            As[c][l] = at[(size_t)(b*L_ + l0 + l)*C_ + c0 + c];
        }
        #pragma unroll
        for (int i=0;i<4;++i) {
            int idx = tid + i*256;
            int o = idx >> 4, c = idx & 15;
            Bs[c][o] = wo[(size_t)(o0 + o)*C_ + c0 + c];
        }
        __syncthreads();
        #pragma unroll
        for (int cc=0;cc<16;++cc) {
            float a[4], bb[4];
            #pragma unroll
            for (int i=0;i<4;++i) a[i]  = As[cc][tx*4+i];
            #pragma unroll
            for (int i=0;i<4;++i) bb[i] = Bs[cc][ty*4+i];
            #pragma unroll
            for (int oi=0;oi<4;++oi)
                #pragma unroll
                for (int li=0;li<4;++li)
                    acc[oi][li] += bb[oi]*a[li];
        }
        __syncthreads();
    }
    #pragma unroll
    for (int oi=0;oi<4;++oi) {
        int o = o0 + ty*4 + oi;
        float bias = bo[o];
        float4 r;
        r.x = acc[oi][0] + bias;
        r.y = acc[oi][1] + bias;
        r.z = acc[oi][2] + bias;
        r.w = acc[oi][3] + bias;
        *reinterpret_cast<float4*>(&out[((size_t)b*C_ + o)*L_ + l0 + tx*4]) = r;
    }
}

extern "C" void kernel_launch(void* const* d_in, const int* in_sizes, int n_in,
                              void* d_out, int out_size, void* d_ws, size_t ws_size,
                              hipStream_t stream) {
    const float* queries = (const float*)d_in[0];
    const float* keys    = (const float*)d_in[1];
    const float* values  = (const float*)d_in[2];
    const float* wq = (const float*)d_in[3];
    const float* bq = (const float*)d_in[4];
    const float* wk = (const float*)d_in[5];
    const float* bk = (const float*)d_in[6];
    const float* wv = (const float*)d_in[7];
    const float* bv = (const float*)d_in[8];
    const float* wo = (const float*)d_in[9];
    const float* bo = (const float*)d_in[10];
    float* out = (float*)d_out;

    const size_t tensor_elems = (size_t)B_ * L_ * C_; // 2,097,152
    float* qt = (float*)d_ws;
    float* kt = qt + tensor_elems;
    float* vt = kt + tensor_elems;
    float* at = vt + tensor_elems;

    dim3 blk(16,16);
    qkv_proj<<<dim3(L_/64, C_/64, B_*3), blk, 0, stream>>>(
        queries, keys, values, wq, bq, wk, bk, wv, bv, qt, kt, vt);
    local_attn<<<dim3(H_/4, HEADS_, B_), 256, 0, stream>>>(qt, kt, vt, at);
    out_proj<<<dim3(L_/64, C_/64, B_), blk, 0, stream>>>(at, wo, bo, out);
}